// Round 14
// baseline (79.139 us; speedup 1.0000x reference)
//
#include <hip/hip_runtime.h>

typedef unsigned short u16;
typedef __attribute__((ext_vector_type(8))) __bf16 bf16x8;
typedef __attribute__((ext_vector_type(4))) float f32x4;

#define DI __device__ __forceinline__

DI u16 f2b(float f){ union{float f; unsigned u;} x; x.f = f; unsigned u = x.u;
  return (u16)((u + 0x7FFFu + ((u>>16)&1u)) >> 16); }

#define NCH 16   // number of chunks
#define CLEN 64  // chunk length  (NCH*CLEN == L == 1024)

// ---------------- prep: cast x->bf16 (blocks 0..511) + 5 weight transposes ----------------
__global__ __launch_bounds__(256) void k_prep(const float* __restrict__ x, u16* __restrict__ xb,
                            const float* w0, const float* w1, const float* w2, const float* w3, const float* w4,
                            u16* t0, u16* t1, u16* t2, u16* t3, u16* t4) {
  __shared__ u16 tile[32][33];
  int z = blockIdx.x;
  int t = threadIdx.x;
  if (z < 512) {
    int i = (z*256 + t)*8;
    float4 a = *(const float4*)(x+i);
    float4 b = *(const float4*)(x+i+4);
    unsigned o0 = (unsigned)f2b(a.x) | ((unsigned)f2b(a.y)<<16);
    unsigned o1 = (unsigned)f2b(a.z) | ((unsigned)f2b(a.w)<<16);
    unsigned o2 = (unsigned)f2b(b.x) | ((unsigned)f2b(b.y)<<16);
    unsigned o3 = (unsigned)f2b(b.z) | ((unsigned)f2b(b.w)<<16);
    *(uint4*)(xb+i) = make_uint4(o0,o1,o2,o3);
    return;
  }
  z -= 512;
  int which = z >> 8;       // 0..4
  int rem = z & 255;
  const float* src; u16* dst; int K, N;
  if (which==0){src=w0;dst=t0;K=512;N=512;}
  else if(which==1){src=w1;dst=t1;K=512;N=512;}
  else if(which==2){src=w2;dst=t2;K=512;N=512;}
  else if(which==3){src=w3;dst=t3;K=512;N=256;}
  else             {src=w4;dst=t4;K=512;N=512;}
  int n0 = (rem & 15)*32, k0 = (rem >> 4)*32;
  if (n0 >= N) return;
  int tx = t & 31, ty = t >> 5; // 32 x 8
  #pragma unroll
  for (int r = 0; r < 4; r++) tile[ty + 8*r][tx] = f2b(src[(k0 + ty + 8*r)*N + n0 + tx]);
  __syncthreads();
  #pragma unroll
  for (int r = 0; r < 4; r++) dst[(n0 + ty + 8*r)*K + k0 + tx] = tile[tx][ty + 8*r];
}

// ============ 512-thread, 128(M)x64(N)-tile MFMA mainloop, BK=64, dbuf, 2-step prefetch ============
// 8 waves = 4M x 2N of 32x32 quadrants. Padded LDS (conflict-free), one barrier per K-step.
#define GEMM128_LOOP(APTR, BPTR)                                                       \
  __shared__ short As[2][128][72];                                                     \
  __shared__ short Bs[2][64][72];                                                      \
  int t = threadIdx.x;                                                                 \
  int lane = t & 63, wid = t >> 6;          /* wid 0..7 */                             \
  int wm = (wid>>1)*32, wn = (wid&1)*32;    /* 4M x 2N */                              \
  int lr = lane & 15, ls = lane >> 4;                                                  \
  int srA = t >> 2, scA = (t & 3)*16;       /* A: 128 rows x 4x16 cols */              \
  int srB = t >> 3, scB = (t & 7)*8;        /* B: 64 rows x 8x8 cols */                \
  f32x4 acc[2][2];                                                                     \
  { f32x4 z_={0.f,0.f,0.f,0.f}; acc[0][0]=z_;acc[0][1]=z_;acc[1][0]=z_;acc[1][1]=z_; } \
  const u16* gA = (APTR) + (bm+srA)*512 + scA;                                         \
  const u16* gB = (BPTR) + (bn+srB)*512 + scB;                                         \
  bf16x8 rA0 = *(const bf16x8*)(gA);     bf16x8 rA1 = *(const bf16x8*)(gA+8);          \
  bf16x8 rB0 = *(const bf16x8*)(gB);                                                   \
  bf16x8 nA0 = *(const bf16x8*)(gA+64);  bf16x8 nA1 = *(const bf16x8*)(gA+72);         \
  bf16x8 nB0 = *(const bf16x8*)(gB+64);                                                \
  *(bf16x8*)&As[0][srA][scA] = rA0; *(bf16x8*)&As[0][srA][scA+8] = rA1;                \
  *(bf16x8*)&Bs[0][srB][scB] = rB0;                                                    \
  __syncthreads();                                                                     \
  _Pragma("unroll")                                                                    \
  for (int st = 0; st < 8; st++) {                                                     \
    int cur = st & 1;                                                                  \
    bf16x8 af_[2][2], bf_[2][2];                                                       \
    _Pragma("unroll")                                                                  \
    for (int ks = 0; ks < 2; ks++) {                                                   \
      _Pragma("unroll")                                                                \
      for (int mi = 0; mi < 2; mi++) {                                                 \
        af_[mi][ks] = *(const bf16x8*)&As[cur][wm+mi*16+lr][ks*32+ls*8];               \
        bf_[mi][ks] = *(const bf16x8*)&Bs[cur][wn+mi*16+lr][ks*32+ls*8];               \
      }                                                                                \
    }                                                                                  \
    if (st < 7) {                                                                      \
      *(bf16x8*)&As[cur^1][srA][scA] = nA0; *(bf16x8*)&As[cur^1][srA][scA+8] = nA1;    \
      *(bf16x8*)&Bs[cur^1][srB][scB] = nB0;                                            \
    }                                                                                  \
    if (st < 6) {                                                                      \
      int kk = (st+2)*64;                                                              \
      nA0 = *(const bf16x8*)(gA+kk);  nA1 = *(const bf16x8*)(gA+kk+8);                 \
      nB0 = *(const bf16x8*)(gB+kk);                                                   \
    }                                                                                  \
    _Pragma("unroll")                                                                  \
    for (int ks = 0; ks < 2; ks++)                                                     \
      _Pragma("unroll")                                                                \
      for (int mi = 0; mi < 2; mi++)                                                   \
        _Pragma("unroll")                                                              \
        for (int ni = 0; ni < 2; ni++)                                                 \
          acc[mi][ni] = __builtin_amdgcn_mfma_f32_16x16x32_bf16(af_[mi][ks], bf_[ni][ks], acc[mi][ni], 0,0,0); \
    __syncthreads();                                                                   \
  }

// ---------------- fused first-layer GEMM over concatenated BT [1792][512] ----------------
__global__ __launch_bounds__(512) void k_gemm4(const u16* __restrict__ A, const u16* __restrict__ BTF,
                       const float* __restrict__ kb1, const float* __restrict__ qb1,
                       const float* __restrict__ vb,  const float* __restrict__ gbias1,
                       float* __restrict__ Hke, float* __restrict__ Hqe,
                       float* __restrict__ V,   float* __restrict__ Hg) {
  int bm = blockIdx.y*128, bn = blockIdx.x*64;
  GEMM128_LOOP(A, BTF)
  float* C; const float* bias; int nstr, nb; bool gel;
  if (bn < 512)       { C=Hke; bias=kb1;    nstr=512; nb=bn;      gel=true;  }
  else if (bn < 1024) { C=Hqe; bias=qb1;    nstr=512; nb=bn-512;  gel=true;  }
  else if (bn < 1536) { C=V;   bias=vb;     nstr=512; nb=bn-1024; gel=false; }
  else                { C=Hg;  bias=gbias1; nstr=256; nb=bn-1536; gel=true;  }
  #pragma unroll
  for (int mi = 0; mi < 2; mi++)
    #pragma unroll
    for (int ni = 0; ni < 2; ni++)
      #pragma unroll
      for (int r = 0; r < 4; r++) {
        int grow = bm + wm + mi*16 + ls*4 + r;
        int gcol = nb + wn + ni*16 + lr;
        float v = acc[mi][ni][r] + bias[gcol];
        if (gel) v = 0.5f*v*(1.0f + erff(v*0.70710678118654752f));
        C[grow*nstr + gcol] = v;
      }
}

// ---------------- final GEMM: out = resid + hln @ oT + bias (same 512-thread structure) ----------------
__global__ __launch_bounds__(512) void k_gemm_out(const u16* __restrict__ A, const u16* __restrict__ BT,
                       const float* __restrict__ bias, const float* __restrict__ resid,
                       float* __restrict__ C) {
  int bm = blockIdx.y*128, bn = blockIdx.x*64;
  GEMM128_LOOP(A, BT)
  #pragma unroll
  for (int mi = 0; mi < 2; mi++)
    #pragma unroll
    for (int ni = 0; ni < 2; ni++)
      #pragma unroll
      for (int r = 0; r < 4; r++) {
        int grow = bm + wm + mi*16 + ls*4 + r;
        int gcol = bn + wn + ni*16 + lr;
        float v = acc[mi][ni][r] + bias[gcol] + resid[grow*512 + gcol];
        C[grow*512 + gcol] = v;
      }
}

// ---------------- phases / features: one wave per row ----------------
__global__ __launch_bounds__(256) void k_phase(const float* __restrict__ Hke, const float* __restrict__ Hqe,
                        const float* __restrict__ Hg,
                        const float* __restrict__ kw2, const float* __restrict__ kb2,
                        const float* __restrict__ qw2, const float* __restrict__ qb2,
                        const float* __restrict__ gw2, const float* __restrict__ gb2,
                        const float* __restrict__ setw, const float* __restrict__ posw,
                        const float* __restrict__ freqs,
                        float* __restrict__ ub, float* __restrict__ ab) {
  int t = threadIdx.x;
  int wid = t >> 6, lane = t & 63;
  int r = blockIdx.x*4 + wid;
  int l = r & 1023;
  int p = lane & 15, s = lane >> 4;
  const float* hk = Hke + r*512 + s*128;
  const float* hq = Hqe + r*512 + s*128;
  float kps = 0.f, qps = 0.f;
  for (int i0 = 0; i0 < 128; i0 += 4) {
    float4 hkv = *(const float4*)(hk + i0);
    float4 hqv = *(const float4*)(hq + i0);
    int kb = (s*128 + i0)*16 + p;
    kps += hkv.x * kw2[kb];      qps += hqv.x * qw2[kb];
    kps += hkv.y * kw2[kb+16];   qps += hqv.y * qw2[kb+16];
    kps += hkv.z * kw2[kb+32];   qps += hqv.z * qw2[kb+32];
    kps += hkv.w * kw2[kb+48];   qps += hqv.w * qw2[kb+48];
  }
  kps += __shfl_xor(kps, 16); kps += __shfl_xor(kps, 32);
  qps += __shfl_xor(qps, 16); qps += __shfl_xor(qps, 32);
  const float PI = 3.14159265358979323846f;
  float kph = tanhf(kps + kb2[p]) * PI;
  float qph = tanhf(qps + qb2[p]) * PI;
  const float* hg = Hg + r*256;
  float4 hgv = *(const float4*)(hg + lane*4);
  float gp = hgv.x*gw2[lane*4] + hgv.y*gw2[lane*4+1]
           + hgv.z*gw2[lane*4+2] + hgv.w*gw2[lane*4+3];
  #pragma unroll
  for (int m = 1; m <= 32; m <<= 1) gp += __shfl_xor(gp, m);
  float gate = 1.f/(1.f + expf(-(gp + gb2[0])));
  float pph = (float)l * freqs[p] * 6.2831853071795864769f;
  float s0=setw[0], s1=setw[1], s2=setw[2], s3=setw[3];
  float mx = fmaxf(fmaxf(s0,s1), fmaxf(s2,s3));
  float e0=expf(s0-mx), e1=expf(s1-mx), e2=expf(s2-mx), e3=expf(s3-mx);
  float esum = e0+e1+e2+e3;
  int si = p >> 2;
  float wsel = (si==0? e0 : si==1? e1 : si==2? e2 : e3) / esum;
  float sigpw = 1.f/(1.f + expf(-posw[0]));
  float invnorm = rsqrtf((float)(l+1) * 4.0f);
  if (lane < 16) {
    float sk, ck, sq, cq, sp, cp;
    sincosf(kph, &sk, &ck);
    sincosf(qph, &sq, &cq);
    sincosf(pph, &sp, &cp);
    float* urow = ub + r*64;
    float* arow = ab + r*64;
    urow[p]      = ck;
    urow[16 + p] = sk;
    urow[32 + p] = cp;
    urow[48 + p] = sp;
    float ga = gate * wsel * invnorm;
    float pa = (1.f - gate) * sigpw * invnorm;
    arow[p]      = ga * cq;
    arow[16 + p] = ga * sq;
    arow[32 + p] = pa * cp;
    arow[48 + p] = pa * sp;
  }
}

// ---------------- scan pass A: per-chunk partial sums P[b][c][k][d] ----------------
__global__ __launch_bounds__(256) void k_scanA(const float* __restrict__ ub, const float* __restrict__ V,
                        float* __restrict__ P) {
  __shared__ float ul[CLEN][64];
  __shared__ float vl[CLEN][64];
  int t = threadIdx.x;
  int d0 = blockIdx.x*64; int c = blockIdx.y; int b = blockIdx.z;
  int srow = t >> 2, scol = (t & 3)*16;
  {
    const float* up = ub + (b*1024 + c*CLEN + srow)*64 + scol;
    *(float4*)&ul[srow][scol]    = *(const float4*)up;
    *(float4*)&ul[srow][scol+4]  = *(const float4*)(up+4);
    *(float4*)&ul[srow][scol+8]  = *(const float4*)(up+8);
    *(float4*)&ul[srow][scol+12] = *(const float4*)(up+12);
    const float* vp = V + (b*1024 + c*CLEN + srow)*512 + d0 + scol;
    *(float4*)&vl[srow][scol]    = *(const float4*)vp;
    *(float4*)&vl[srow][scol+4]  = *(const float4*)(vp+4);
    *(float4*)&vl[srow][scol+8]  = *(const float4*)(vp+8);
    *(float4*)&vl[srow][scol+12] = *(const float4*)(vp+12);
  }
  __syncthreads();
  int dd = t & 63, kg = t >> 6;
  float acc[16];
  #pragma unroll
  for (int i=0;i<16;i++) acc[i]=0.f;
  for (int tt = 0; tt < CLEN; tt++) {
    float vv = vl[tt][dd];
    #pragma unroll
    for (int i=0;i<16;i++) acc[i] += ul[tt][kg*16+i]*vv;
  }
  float* pp = P + (((b*NCH + c)*64) + kg*16)*512 + d0 + dd;
  #pragma unroll
  for (int i=0;i<16;i++) pp[i*512] = acc[i];
}

// ---------------- scan pass B: in-place exclusive prefix over chunks ----------------
__global__ __launch_bounds__(256) void k_scanB(float* __restrict__ P) {
  int tid = blockIdx.x*256 + threadIdx.x;   // 0..65535 = B*64*512
  int b = tid >> 15;
  int k = (tid >> 9) & 63;
  int d = tid & 511;
  float run = 0.f;
  float* base = P + ((b*NCH)*64 + k)*512 + d;
  for (int c = 0; c < NCH; c++) {
    float v = base[c*64*512];
    base[c*64*512] = run;
    run += v;
  }
}

// ---------------- scan pass C: intra-chunk sweep, 4 lanes per d, s[16] in regs ----------------
__global__ __launch_bounds__(256) void k_scanC(const float* __restrict__ ub, const float* __restrict__ ab,
                        const float* __restrict__ V, const float* __restrict__ P,
                        float* __restrict__ h) {
  __shared__ float ul[CLEN][64];
  __shared__ float al[CLEN][64];
  int t = threadIdx.x;
  int c = blockIdx.y; int b = blockIdx.z;
  int srow = t >> 2, scol = (t & 3)*16;
  {
    const float* up = ub + (b*1024 + c*CLEN + srow)*64 + scol;
    *(float4*)&ul[srow][scol]    = *(const float4*)up;
    *(float4*)&ul[srow][scol+4]  = *(const float4*)(up+4);
    *(float4*)&ul[srow][scol+8]  = *(const float4*)(up+8);
    *(float4*)&ul[srow][scol+12] = *(const float4*)(up+12);
    const float* ap = ab + (b*1024 + c*CLEN + srow)*64 + scol;
    *(float4*)&al[srow][scol]    = *(const float4*)ap;
    *(float4*)&al[srow][scol+4]  = *(const float4*)(ap+4);
    *(float4*)&al[srow][scol+8]  = *(const float4*)(ap+8);
    *(float4*)&al[srow][scol+12] = *(const float4*)(ap+12);
  }
  __syncthreads();
  int kg = t & 3;          // 4 lanes share one d; each owns 16 features
  int di = t >> 2;         // 0..63
  int d = blockIdx.x*64 + di;
  float s[16];
  const float* pb = P + ((b*NCH + c)*64 + kg*16)*512 + d;
  #pragma unroll
  for (int k = 0; k < 16; k++) s[k] = pb[k*512];
  const float* vrow = V + (b*1024 + c*CLEN)*512 + d;
  float* hrow = h + (b*1024 + c*CLEN)*512 + d;
  const float4* ul4 = (const float4*)&ul[0][0];
  const float4* al4 = (const float4*)&al[0][0];
  for (int tt = 0; tt < CLEN; tt++) {
    float vv = vrow[tt*512];
    float4 u0 = ul4[tt*16 + kg*4 + 0];
    float4 u1 = ul4[tt*16 + kg*4 + 1];
    float4 u2 = ul4[tt*16 + kg*4 + 2];
    float4 u3 = ul4[tt*16 + kg*4 + 3];
    float4 a0 = al4[tt*16 + kg*4 + 0];
    float4 a1 = al4[tt*16 + kg*4 + 1];
    float4 a2 = al4[tt*16 + kg*4 + 2];
    float4 a3 = al4[tt*16 + kg*4 + 3];
    float h0=0.f, h1=0.f, h2=0.f, h3=0.f;
    s[0]  += u0.x*vv; h0 += a0.x*s[0];
    s[1]  += u0.y*vv; h1 += a0.y*s[1];
    s[2]  += u0.z*vv; h2 += a0.z*s[2];
    s[3]  += u0.w*vv; h3 += a0.w*s[3];
    s[4]  += u1.x*vv; h0 += a1.x*s[4];
    s[5]  += u1.y*vv; h1 += a1.y*s[5];
    s[6]  += u1.z*vv; h2 += a1.z*s[6];
    s[7]  += u1.w*vv; h3 += a1.w*s[7];
    s[8]  += u2.x*vv; h0 += a2.x*s[8];
    s[9]  += u2.y*vv; h1 += a2.y*s[9];
    s[10] += u2.z*vv; h2 += a2.z*s[10];
    s[11] += u2.w*vv; h3 += a2.w*s[11];
    s[12] += u3.x*vv; h0 += a3.x*s[12];
    s[13] += u3.y*vv; h1 += a3.y*s[13];
    s[14] += u3.z*vv; h2 += a3.z*s[14];
    s[15] += u3.w*vv; h3 += a3.w*s[15];
    float hp = (h0+h1)+(h2+h3);
    hp += __shfl_xor(hp, 1);
    hp += __shfl_xor(hp, 2);
    if (kg == 0) hrow[tt*512] = hp;
  }
}

// ---------------- layernorm: one wave per row, bf16 out ----------------
__global__ __launch_bounds__(256) void k_ln(const float* __restrict__ h, const float* __restrict__ g,
                     const float* __restrict__ bta, u16* __restrict__ hln) {
  int t = threadIdx.x;
  int wid = t >> 6, lane = t & 63;
  int r = blockIdx.x*4 + wid;
  const float* hr = h + r*512;
  float4 v0 = *(const float4*)(hr + lane*8);
  float4 v1 = *(const float4*)(hr + lane*8 + 4);
  float vals[8] = {v0.x,v0.y,v0.z,v0.w,v1.x,v1.y,v1.z,v1.w};
  float sum = 0.f, sq = 0.f;
  #pragma unroll
  for (int i=0;i<8;i++){ sum += vals[i]; sq += vals[i]*vals[i]; }
  #pragma unroll
  for (int m = 1; m <= 32; m <<= 1){ sum += __shfl_xor(sum, m); sq += __shfl_xor(sq, m); }
  float mu = sum * (1.f/512.f);
  float var = sq * (1.f/512.f) - mu*mu;
  float rstd = rsqrtf(var + 1e-5f);
  unsigned o[4];
  #pragma unroll
  for (int i=0;i<4;i++){
    u16 lo = f2b((vals[2*i]  -mu)*rstd*g[lane*8+2*i]   + bta[lane*8+2*i]);
    u16 hi = f2b((vals[2*i+1]-mu)*rstd*g[lane*8+2*i+1] + bta[lane*8+2*i+1]);
    o[i] = (unsigned)lo | ((unsigned)hi << 16);
  }
  uint4 ov = make_uint4(o[0],o[1],o[2],o[3]);
  *(uint4*)(hln + r*512 + lane*8) = ov;
}

extern "C" void kernel_launch(void* const* d_in, const int* in_sizes, int n_in,
                              void* d_out, int out_size, void* d_ws, size_t ws_size,
                              hipStream_t stream) {
  const float* x       = (const float*)d_in[0];
  const float* ke_w1   = (const float*)d_in[1];
  const float* ke_b1   = (const float*)d_in[2];
  const float* ke_w2   = (const float*)d_in[3];
  const float* ke_b2   = (const float*)d_in[4];
  const float* qe_w1   = (const float*)d_in[5];
  const float* qe_b1   = (const float*)d_in[6];
  const float* qe_w2   = (const float*)d_in[7];
  const float* qe_b2   = (const float*)d_in[8];
  const float* v_w     = (const float*)d_in[9];
  const float* v_b     = (const float*)d_in[10];
  const float* ln_g    = (const float*)d_in[11];
  const float* ln_b    = (const float*)d_in[12];
  const float* out_w   = (const float*)d_in[13];
  const float* out_b   = (const float*)d_in[14];
  const float* setw    = (const float*)d_in[15];
  const float* posw    = (const float*)d_in[16];
  const float* gate_w1 = (const float*)d_in[17];
  const float* gate_b1 = (const float*)d_in[18];
  const float* gate_w2 = (const float*)d_in[19];
  const float* gate_b2 = (const float*)d_in[20];
  const float* freqs   = (const float*)d_in[21];
  float* out = (float*)d_out;

  char* ws = (char*)d_ws;
  u16*   xb  = (u16*)(ws + 0);            // 2048x512 bf16 (2 MB)
  u16*   BTF = (u16*)(ws + 2097152);      // 1792x512 bf16 (1.75 MB)
  u16*   oT  = (u16*)(ws + 3932160);      // 512x512 bf16 (512 KB)
  float* Hke = (float*)(ws + 4456448);    // 2048x512 f32 (reused as h)
  float* Hqe = (float*)(ws + 8650752);    // 2048x512 f32 (reused as hln bf16)
  float* Hg  = (float*)(ws + 12845056);   // 2048x256 f32
  float* V   = (float*)(ws + 14942208);   // 2048x512 f32
  float* ubf = (float*)(ws + 19136512);   // 2048x64 f32
  float* abf = (float*)(ws + 19660800);   // 2048x64 f32
  float* P   = (float*)(ws + 20185088);   // 2*16*64*512 f32 = 4 MB (ends 24379392)
  float* h   = Hke;                       // overlay (Hke consumed by k_phase)
  u16*   hln = (u16*)Hqe;                 // overlay (Hqe consumed by k_phase)

  u16* keT = BTF;                // rows 0..511
  u16* qeT = BTF + 512*512;      // rows 512..1023
  u16* vT  = BTF + 1024*512;     // rows 1024..1535
  u16* gT  = BTF + 1536*512;     // rows 1536..1791

  k_prep<<<512 + 5*256, 256, 0, stream>>>(x, xb, ke_w1,qe_w1,v_w,gate_w1,out_w,
                                          keT,qeT,vT,gT,oT);
  k_gemm4<<<dim3(28,16),512,0,stream>>>(xb, BTF, ke_b1, qe_b1, v_b, gate_b1,
                                        Hke, Hqe, V, Hg);
  k_phase<<<512,256,0,stream>>>(Hke,Hqe,Hg, ke_w2,ke_b2, qe_w2,qe_b2,
                                gate_w2,gate_b2, setw,posw,freqs, ubf,abf);
  k_scanA<<<dim3(8,NCH,2),256,0,stream>>>(ubf, V, P);
  k_scanB<<<256,256,0,stream>>>(P);
  k_scanC<<<dim3(8,NCH,2),256,0,stream>>>(ubf, abf, V, P, h);
  k_ln<<<512,256,0,stream>>>(h, ln_g, ln_b, hln);
  k_gemm_out<<<dim3(8,16),512,0,stream>>>(hln, oT, out_b, x, out);
}

// Round 15
// 77.856 us; speedup vs baseline: 1.0165x; 1.0165x over previous
//
#include <hip/hip_runtime.h>

typedef unsigned short u16;
typedef __attribute__((ext_vector_type(8))) __bf16 bf16x8;
typedef __attribute__((ext_vector_type(4))) float f32x4;

#define DI __device__ __forceinline__

DI u16 f2b(float f){ union{unsigned u; float f;} x; x.f = f; unsigned u = x.u;
  return (u16)((u + 0x7FFFu + ((u>>16)&1u)) >> 16); }

#define NCH 16   // number of chunks
#define CLEN 64  // chunk length  (NCH*CLEN == L == 1024)

// ---------------- prep: cast x->bf16 (blocks 0..511) + 5 weight transposes ----------------
__global__ __launch_bounds__(256) void k_prep(const float* __restrict__ x, u16* __restrict__ xb,
                            const float* w0, const float* w1, const float* w2, const float* w3, const float* w4,
                            u16* t0, u16* t1, u16* t2, u16* t3, u16* t4) {
  __shared__ u16 tile[32][33];
  int z = blockIdx.x;
  int t = threadIdx.x;
  if (z < 512) {
    int i = (z*256 + t)*8;
    float4 a = *(const float4*)(x+i);
    float4 b = *(const float4*)(x+i+4);
    unsigned o0 = (unsigned)f2b(a.x) | ((unsigned)f2b(a.y)<<16);
    unsigned o1 = (unsigned)f2b(a.z) | ((unsigned)f2b(a.w)<<16);
    unsigned o2 = (unsigned)f2b(b.x) | ((unsigned)f2b(b.y)<<16);
    unsigned o3 = (unsigned)f2b(b.z) | ((unsigned)f2b(b.w)<<16);
    *(uint4*)(xb+i) = make_uint4(o0,o1,o2,o3);
    return;
  }
  z -= 512;
  int which = z >> 8;       // 0..4
  int rem = z & 255;
  const float* src; u16* dst; int K, N;
  if (which==0){src=w0;dst=t0;K=512;N=512;}
  else if(which==1){src=w1;dst=t1;K=512;N=512;}
  else if(which==2){src=w2;dst=t2;K=512;N=512;}
  else if(which==3){src=w3;dst=t3;K=512;N=256;}
  else             {src=w4;dst=t4;K=512;N=512;}
  int n0 = (rem & 15)*32, k0 = (rem >> 4)*32;
  if (n0 >= N) return;
  int tx = t & 31, ty = t >> 5; // 32 x 8
  #pragma unroll
  for (int r = 0; r < 4; r++) tile[ty + 8*r][tx] = f2b(src[(k0 + ty + 8*r)*N + n0 + tx]);
  __syncthreads();
  #pragma unroll
  for (int r = 0; r < 4; r++) dst[(n0 + ty + 8*r)*K + k0 + tx] = tile[tx][ty + 8*r];
}

// ============ 64x64-tile MFMA mainloop, BK=64, dbuf LDS, 2-step-ahead prefetch ============
// (used by gemm_out; proven R7 structure — 256 blocks keeps all CUs busy)
#define GEMM64_LOOP(APTR, BPTR)                                                       \
  __shared__ short As[2][64][72];                                                     \
  __shared__ short Bs[2][64][72];                                                     \
  int t = threadIdx.x;                                                                \
  int lane = t & 63, wid = t >> 6;                                                    \
  int wm = (wid>>1)*32, wn = (wid&1)*32;                                              \
  int lr = lane & 15, ls = lane >> 4;                                                 \
  int srow = t >> 2, scol = (t & 3)*16;                                               \
  f32x4 acc[2][2];                                                                    \
  { f32x4 z_={0.f,0.f,0.f,0.f}; acc[0][0]=z_;acc[0][1]=z_;acc[1][0]=z_;acc[1][1]=z_; }\
  const u16* gA = (APTR) + (bm+srow)*512 + scol;                                      \
  const u16* gB = (BPTR) + (bn+srow)*512 + scol;                                      \
  bf16x8 rA0 = *(const bf16x8*)(gA);      bf16x8 rA1 = *(const bf16x8*)(gA+8);        \
  bf16x8 rB0 = *(const bf16x8*)(gB);      bf16x8 rB1 = *(const bf16x8*)(gB+8);        \
  bf16x8 nA0 = *(const bf16x8*)(gA+64);   bf16x8 nA1 = *(const bf16x8*)(gA+72);       \
  bf16x8 nB0 = *(const bf16x8*)(gB+64);   bf16x8 nB1 = *(const bf16x8*)(gB+72);       \
  *(bf16x8*)&As[0][srow][scol] = rA0; *(bf16x8*)&As[0][srow][scol+8] = rA1;           \
  *(bf16x8*)&Bs[0][srow][scol] = rB0; *(bf16x8*)&Bs[0][srow][scol+8] = rB1;           \
  __syncthreads();                                                                    \
  _Pragma("unroll")                                                                   \
  for (int st = 0; st < 8; st++) {                                                    \
    int cur = st & 1;                                                                 \
    bf16x8 af_[2][2], bf_[2][2];                                                      \
    _Pragma("unroll")                                                                 \
    for (int ks = 0; ks < 2; ks++) {                                                  \
      _Pragma("unroll")                                                               \
      for (int mi = 0; mi < 2; mi++) {                                                \
        af_[mi][ks] = *(const bf16x8*)&As[cur][wm+mi*16+lr][ks*32+ls*8];              \
        bf_[mi][ks] = *(const bf16x8*)&Bs[cur][wn+mi*16+lr][ks*32+ls*8];              \
      }                                                                               \
    }                                                                                 \
    if (st < 7) {                                                                     \
      *(bf16x8*)&As[cur^1][srow][scol] = nA0; *(bf16x8*)&As[cur^1][srow][scol+8] = nA1; \
      *(bf16x8*)&Bs[cur^1][srow][scol] = nB0; *(bf16x8*)&Bs[cur^1][srow][scol+8] = nB1; \
    }                                                                                  \
    if (st < 6) {                                                                      \
      int kk = (st+2)*64;                                                              \
      nA0 = *(const bf16x8*)(gA+kk);    nA1 = *(const bf16x8*)(gA+kk+8);               \
      nB0 = *(const bf16x8*)(gB+kk);    nB1 = *(const bf16x8*)(gB+kk+8);               \
    }                                                                                  \
    _Pragma("unroll")                                                                  \
    for (int ks = 0; ks < 2; ks++)                                                     \
      _Pragma("unroll")                                                                \
      for (int mi = 0; mi < 2; mi++)                                                   \
        _Pragma("unroll")                                                              \
        for (int ni = 0; ni < 2; ni++)                                                 \
          acc[mi][ni] = __builtin_amdgcn_mfma_f32_16x16x32_bf16(af_[mi][ks], bf_[ni][ks], acc[mi][ni], 0,0,0); \
    __syncthreads();                                                                   \
  }

// ---------------- fused first-layer GEMM: 512 threads, 128(M)x64(N) tile, BK=64 dbuf ----------------
// 8 waves = 4M x 2N of 32x32 quadrants; 448 blocks (~1.75/CU). Best measured (R13).
__global__ __launch_bounds__(512) void k_gemm4(const u16* __restrict__ A, const u16* __restrict__ BTF,
                       const float* __restrict__ kb1, const float* __restrict__ qb1,
                       const float* __restrict__ vb,  const float* __restrict__ gbias1,
                       float* __restrict__ Hke, float* __restrict__ Hqe,
                       float* __restrict__ V,   float* __restrict__ Hg) {
  __shared__ short As[2][128][72];
  __shared__ short Bs[2][64][72];
  int t = threadIdx.x;
  int lane = t & 63, wid = t >> 6;          // wid 0..7
  int wm = (wid>>1)*32, wn = (wid&1)*32;    // 4M x 2N
  int lr = lane & 15, ls = lane >> 4;
  int bm = blockIdx.y*128, bn = blockIdx.x*64;
  int srA = t >> 2, scA = (t & 3)*16;       // A: 128 rows x 4x16 cols
  int srB = t >> 3, scB = (t & 7)*8;        // B: 64 rows x 8x8 cols
  f32x4 acc[2][2];
  { f32x4 z_={0.f,0.f,0.f,0.f}; acc[0][0]=z_;acc[0][1]=z_;acc[1][0]=z_;acc[1][1]=z_; }
  const u16* gA = A   + (bm+srA)*512 + scA;
  const u16* gB = BTF + (bn+srB)*512 + scB;
  bf16x8 rA0 = *(const bf16x8*)(gA);     bf16x8 rA1 = *(const bf16x8*)(gA+8);
  bf16x8 rB0 = *(const bf16x8*)(gB);
  bf16x8 nA0 = *(const bf16x8*)(gA+64);  bf16x8 nA1 = *(const bf16x8*)(gA+72);
  bf16x8 nB0 = *(const bf16x8*)(gB+64);
  *(bf16x8*)&As[0][srA][scA] = rA0; *(bf16x8*)&As[0][srA][scA+8] = rA1;
  *(bf16x8*)&Bs[0][srB][scB] = rB0;
  __syncthreads();
  #pragma unroll
  for (int st = 0; st < 8; st++) {
    int cur = st & 1;
    bf16x8 af_[2][2], bf_[2][2];
    #pragma unroll
    for (int ks = 0; ks < 2; ks++) {
      #pragma unroll
      for (int mi = 0; mi < 2; mi++) {
        af_[mi][ks] = *(const bf16x8*)&As[cur][wm+mi*16+lr][ks*32+ls*8];
        bf_[mi][ks] = *(const bf16x8*)&Bs[cur][wn+mi*16+lr][ks*32+ls*8];
      }
    }
    if (st < 7) {
      *(bf16x8*)&As[cur^1][srA][scA] = nA0; *(bf16x8*)&As[cur^1][srA][scA+8] = nA1;
      *(bf16x8*)&Bs[cur^1][srB][scB] = nB0;
    }
    if (st < 6) {
      int kk = (st+2)*64;
      nA0 = *(const bf16x8*)(gA+kk);  nA1 = *(const bf16x8*)(gA+kk+8);
      nB0 = *(const bf16x8*)(gB+kk);
    }
    #pragma unroll
    for (int ks = 0; ks < 2; ks++)
      #pragma unroll
      for (int mi = 0; mi < 2; mi++)
        #pragma unroll
        for (int ni = 0; ni < 2; ni++)
          acc[mi][ni] = __builtin_amdgcn_mfma_f32_16x16x32_bf16(af_[mi][ks], bf_[ni][ks], acc[mi][ni], 0,0,0);
    __syncthreads();
  }
  float* C; const float* bias; int nstr, nb; bool gel;
  if (bn < 512)       { C=Hke; bias=kb1;    nstr=512; nb=bn;      gel=true;  }
  else if (bn < 1024) { C=Hqe; bias=qb1;    nstr=512; nb=bn-512;  gel=true;  }
  else if (bn < 1536) { C=V;   bias=vb;     nstr=512; nb=bn-1024; gel=false; }
  else                { C=Hg;  bias=gbias1; nstr=256; nb=bn-1536; gel=true;  }
  #pragma unroll
  for (int mi = 0; mi < 2; mi++)
    #pragma unroll
    for (int ni = 0; ni < 2; ni++)
      #pragma unroll
      for (int r = 0; r < 4; r++) {
        int grow = bm + wm + mi*16 + ls*4 + r;
        int gcol = nb + wn + ni*16 + lr;
        float v = acc[mi][ni][r] + bias[gcol];
        if (gel) v = 0.5f*v*(1.0f + erff(v*0.70710678118654752f));
        C[grow*nstr + gcol] = v;
      }
}

// ---------------- final GEMM: out = resid + hln @ oT + bias ----------------
__global__ __launch_bounds__(256) void k_gemm_out(const u16* __restrict__ A, const u16* __restrict__ BT,
                       const float* __restrict__ bias, const float* __restrict__ resid,
                       float* __restrict__ C) {
  int bm = blockIdx.y*64, bn = blockIdx.x*64;
  GEMM64_LOOP(A, BT)
  #pragma unroll
  for (int mi = 0; mi < 2; mi++)
    #pragma unroll
    for (int ni = 0; ni < 2; ni++)
      #pragma unroll
      for (int r = 0; r < 4; r++) {
        int grow = bm + wm + mi*16 + ls*4 + r;
        int gcol = bn + wn + ni*16 + lr;
        float v = acc[mi][ni][r] + bias[gcol] + resid[grow*512 + gcol];
        C[grow*512 + gcol] = v;
      }
}

// ---------------- phases / features: one wave per row ----------------
__global__ __launch_bounds__(256) void k_phase(const float* __restrict__ Hke, const float* __restrict__ Hqe,
                        const float* __restrict__ Hg,
                        const float* __restrict__ kw2, const float* __restrict__ kb2,
                        const float* __restrict__ qw2, const float* __restrict__ qb2,
                        const float* __restrict__ gw2, const float* __restrict__ gb2,
                        const float* __restrict__ setw, const float* __restrict__ posw,
                        const float* __restrict__ freqs,
                        float* __restrict__ ub, float* __restrict__ ab) {
  int t = threadIdx.x;
  int wid = t >> 6, lane = t & 63;
  int r = blockIdx.x*4 + wid;
  int l = r & 1023;
  int p = lane & 15, s = lane >> 4;
  const float* hk = Hke + r*512 + s*128;
  const float* hq = Hqe + r*512 + s*128;
  float kps = 0.f, qps = 0.f;
  for (int i0 = 0; i0 < 128; i0 += 4) {
    float4 hkv = *(const float4*)(hk + i0);
    float4 hqv = *(const float4*)(hq + i0);
    int kb = (s*128 + i0)*16 + p;
    kps += hkv.x * kw2[kb];      qps += hqv.x * qw2[kb];
    kps += hkv.y * kw2[kb+16];   qps += hqv.y * qw2[kb+16];
    kps += hkv.z * kw2[kb+32];   qps += hqv.z * qw2[kb+32];
    kps += hkv.w * kw2[kb+48];   qps += hqv.w * qw2[kb+48];
  }
  kps += __shfl_xor(kps, 16); kps += __shfl_xor(kps, 32);
  qps += __shfl_xor(qps, 16); qps += __shfl_xor(qps, 32);
  const float PI = 3.14159265358979323846f;
  float kph = tanhf(kps + kb2[p]) * PI;
  float qph = tanhf(qps + qb2[p]) * PI;
  const float* hg = Hg + r*256;
  float4 hgv = *(const float4*)(hg + lane*4);
  float gp = hgv.x*gw2[lane*4] + hgv.y*gw2[lane*4+1]
           + hgv.z*gw2[lane*4+2] + hgv.w*gw2[lane*4+3];
  #pragma unroll
  for (int m = 1; m <= 32; m <<= 1) gp += __shfl_xor(gp, m);
  float gate = 1.f/(1.f + expf(-(gp + gb2[0])));
  float pph = (float)l * freqs[p] * 6.2831853071795864769f;
  float s0=setw[0], s1=setw[1], s2=setw[2], s3=setw[3];
  float mx = fmaxf(fmaxf(s0,s1), fmaxf(s2,s3));
  float e0=expf(s0-mx), e1=expf(s1-mx), e2=expf(s2-mx), e3=expf(s3-mx);
  float esum = e0+e1+e2+e3;
  int si = p >> 2;
  float wsel = (si==0? e0 : si==1? e1 : si==2? e2 : e3) / esum;
  float sigpw = 1.f/(1.f + expf(-posw[0]));
  float invnorm = rsqrtf((float)(l+1) * 4.0f);
  if (lane < 16) {
    float sk, ck, sq, cq, sp, cp;
    sincosf(kph, &sk, &ck);
    sincosf(qph, &sq, &cq);
    sincosf(pph, &sp, &cp);
    float* urow = ub + r*64;
    float* arow = ab + r*64;
    urow[p]      = ck;
    urow[16 + p] = sk;
    urow[32 + p] = cp;
    urow[48 + p] = sp;
    float ga = gate * wsel * invnorm;
    float pa = (1.f - gate) * sigpw * invnorm;
    arow[p]      = ga * cq;
    arow[16 + p] = ga * sq;
    arow[32 + p] = pa * cp;
    arow[48 + p] = pa * sp;
  }
}

// ---------------- scan pass A: per-chunk partial sums P[b][c][k][d] ----------------
__global__ __launch_bounds__(256) void k_scanA(const float* __restrict__ ub, const float* __restrict__ V,
                        float* __restrict__ P) {
  __shared__ float ul[CLEN][64];
  __shared__ float vl[CLEN][64];
  int t = threadIdx.x;
  int d0 = blockIdx.x*64; int c = blockIdx.y; int b = blockIdx.z;
  int srow = t >> 2, scol = (t & 3)*16;
  {
    const float* up = ub + (b*1024 + c*CLEN + srow)*64 + scol;
    *(float4*)&ul[srow][scol]    = *(const float4*)up;
    *(float4*)&ul[srow][scol+4]  = *(const float4*)(up+4);
    *(float4*)&ul[srow][scol+8]  = *(const float4*)(up+8);
    *(float4*)&ul[srow][scol+12] = *(const float4*)(up+12);
    const float* vp = V + (b*1024 + c*CLEN + srow)*512 + d0 + scol;
    *(float4*)&vl[srow][scol]    = *(const float4*)vp;
    *(float4*)&vl[srow][scol+4]  = *(const float4*)(vp+4);
    *(float4*)&vl[srow][scol+8]  = *(const float4*)(vp+8);
    *(float4*)&vl[srow][scol+12] = *(const float4*)(vp+12);
  }
  __syncthreads();
  int dd = t & 63, kg = t >> 6;
  float acc[16];
  #pragma unroll
  for (int i=0;i<16;i++) acc[i]=0.f;
  for (int tt = 0; tt < CLEN; tt++) {
    float vv = vl[tt][dd];
    #pragma unroll
    for (int i=0;i<16;i++) acc[i] += ul[tt][kg*16+i]*vv;
  }
  float* pp = P + (((b*NCH + c)*64) + kg*16)*512 + d0 + dd;
  #pragma unroll
  for (int i=0;i<16;i++) pp[i*512] = acc[i];
}

// ---------------- scan pass B: in-place exclusive prefix over chunks ----------------
__global__ __launch_bounds__(256) void k_scanB(float* __restrict__ P) {
  int tid = blockIdx.x*256 + threadIdx.x;   // 0..65535 = B*64*512
  int b = tid >> 15;
  int k = (tid >> 9) & 63;
  int d = tid & 511;
  float run = 0.f;
  float* base = P + ((b*NCH)*64 + k)*512 + d;
  for (int c = 0; c < NCH; c++) {
    float v = base[c*64*512];
    base[c*64*512] = run;
    run += v;
  }
}

// ---------------- scan pass C: intra-chunk sweep, 4 lanes per d, s[16] in regs ----------------
__global__ __launch_bounds__(256) void k_scanC(const float* __restrict__ ub, const float* __restrict__ ab,
                        const float* __restrict__ V, const float* __restrict__ P,
                        float* __restrict__ h) {
  __shared__ float ul[CLEN][64];
  __shared__ float al[CLEN][64];
  int t = threadIdx.x;
  int c = blockIdx.y; int b = blockIdx.z;
  int srow = t >> 2, scol = (t & 3)*16;
  {
    const float* up = ub + (b*1024 + c*CLEN + srow)*64 + scol;
    *(float4*)&ul[srow][scol]    = *(const float4*)up;
    *(float4*)&ul[srow][scol+4]  = *(const float4*)(up+4);
    *(float4*)&ul[srow][scol+8]  = *(const float4*)(up+8);
    *(float4*)&ul[srow][scol+12] = *(const float4*)(up+12);
    const float* ap = ab + (b*1024 + c*CLEN + srow)*64 + scol;
    *(float4*)&al[srow][scol]    = *(const float4*)ap;
    *(float4*)&al[srow][scol+4]  = *(const float4*)(ap+4);
    *(float4*)&al[srow][scol+8]  = *(const float4*)(ap+8);
    *(float4*)&al[srow][scol+12] = *(const float4*)(ap+12);
  }
  __syncthreads();
  int kg = t & 3;          // 4 lanes share one d; each owns 16 features
  int di = t >> 2;         // 0..63
  int d = blockIdx.x*64 + di;
  float s[16];
  const float* pb = P + ((b*NCH + c)*64 + kg*16)*512 + d;
  #pragma unroll
  for (int k = 0; k < 16; k++) s[k] = pb[k*512];
  const float* vrow = V + (b*1024 + c*CLEN)*512 + d;
  float* hrow = h + (b*1024 + c*CLEN)*512 + d;
  const float4* ul4 = (const float4*)&ul[0][0];
  const float4* al4 = (const float4*)&al[0][0];
  for (int tt = 0; tt < CLEN; tt++) {
    float vv = vrow[tt*512];
    float4 u0 = ul4[tt*16 + kg*4 + 0];
    float4 u1 = ul4[tt*16 + kg*4 + 1];
    float4 u2 = ul4[tt*16 + kg*4 + 2];
    float4 u3 = ul4[tt*16 + kg*4 + 3];
    float4 a0 = al4[tt*16 + kg*4 + 0];
    float4 a1 = al4[tt*16 + kg*4 + 1];
    float4 a2 = al4[tt*16 + kg*4 + 2];
    float4 a3 = al4[tt*16 + kg*4 + 3];
    float h0=0.f, h1=0.f, h2=0.f, h3=0.f;
    s[0]  += u0.x*vv; h0 += a0.x*s[0];
    s[1]  += u0.y*vv; h1 += a0.y*s[1];
    s[2]  += u0.z*vv; h2 += a0.z*s[2];
    s[3]  += u0.w*vv; h3 += a0.w*s[3];
    s[4]  += u1.x*vv; h0 += a1.x*s[4];
    s[5]  += u1.y*vv; h1 += a1.y*s[5];
    s[6]  += u1.z*vv; h2 += a1.z*s[6];
    s[7]  += u1.w*vv; h3 += a1.w*s[7];
    s[8]  += u2.x*vv; h0 += a2.x*s[8];
    s[9]  += u2.y*vv; h1 += a2.y*s[9];
    s[10] += u2.z*vv; h2 += a2.z*s[10];
    s[11] += u2.w*vv; h3 += a2.w*s[11];
    s[12] += u3.x*vv; h0 += a3.x*s[12];
    s[13] += u3.y*vv; h1 += a3.y*s[13];
    s[14] += u3.z*vv; h2 += a3.z*s[14];
    s[15] += u3.w*vv; h3 += a3.w*s[15];
    float hp = (h0+h1)+(h2+h3);
    hp += __shfl_xor(hp, 1);
    hp += __shfl_xor(hp, 2);
    if (kg == 0) hrow[tt*512] = hp;
  }
}

// ---------------- layernorm: one wave per row, bf16 out ----------------
__global__ __launch_bounds__(256) void k_ln(const float* __restrict__ h, const float* __restrict__ g,
                     const float* __restrict__ bta, u16* __restrict__ hln) {
  int t = threadIdx.x;
  int wid = t >> 6, lane = t & 63;
  int r = blockIdx.x*4 + wid;
  const float* hr = h + r*512;
  float4 v0 = *(const float4*)(hr + lane*8);
  float4 v1 = *(const float4*)(hr + lane*8 + 4);
  float vals[8] = {v0.x,v0.y,v0.z,v0.w,v1.x,v1.y,v1.z,v1.w};
  float sum = 0.f, sq = 0.f;
  #pragma unroll
  for (int i=0;i<8;i++){ sum += vals[i]; sq += vals[i]*vals[i]; }
  #pragma unroll
  for (int m = 1; m <= 32; m <<= 1){ sum += __shfl_xor(sum, m); sq += __shfl_xor(sq, m); }
  float mu = sum * (1.f/512.f);
  float var = sq * (1.f/512.f) - mu*mu;
  float rstd = rsqrtf(var + 1e-5f);
  unsigned o[4];
  #pragma unroll
  for (int i=0;i<4;i++){
    u16 lo = f2b((vals[2*i]  -mu)*rstd*g[lane*8+2*i]   + bta[lane*8+2*i]);
    u16 hi = f2b((vals[2*i+1]-mu)*rstd*g[lane*8+2*i+1] + bta[lane*8+2*i+1]);
    o[i] = (unsigned)lo | ((unsigned)hi << 16);
  }
  uint4 ov = make_uint4(o[0],o[1],o[2],o[3]);
  *(uint4*)(hln + r*512 + lane*8) = ov;
}

extern "C" void kernel_launch(void* const* d_in, const int* in_sizes, int n_in,
                              void* d_out, int out_size, void* d_ws, size_t ws_size,
                              hipStream_t stream) {
  const float* x       = (const float*)d_in[0];
  const float* ke_w1   = (const float*)d_in[1];
  const float* ke_b1   = (const float*)d_in[2];
  const float* ke_w2   = (const float*)d_in[3];
  const float* ke_b2   = (const float*)d_in[4];
  const float* qe_w1   = (const float*)d_in[5];
  const float* qe_b1   = (const float*)d_in[6];
  const float* qe_w2   = (const float*)d_in[7];
  const float* qe_b2   = (const float*)d_in[8];
  const float* v_w     = (const float*)d_in[9];
  const float* v_b     = (const float*)d_in[10];
  const float* ln_g    = (const float*)d_in[11];
  const float* ln_b    = (const float*)d_in[12];
  const float* out_w   = (const float*)d_in[13];
  const float* out_b   = (const float*)d_in[14];
  const float* setw    = (const float*)d_in[15];
  const float* posw    = (const float*)d_in[16];
  const float* gate_w1 = (const float*)d_in[17];
  const float* gate_b1 = (const float*)d_in[18];
  const float* gate_w2 = (const float*)d_in[19];
  const float* gate_b2 = (const float*)d_in[20];
  const float* freqs   = (const float*)d_in[21];
  float* out = (float*)d_out;

  char* ws = (char*)d_ws;
  u16*   xb  = (u16*)(ws + 0);            // 2048x512 bf16 (2 MB)
  u16*   BTF = (u16*)(ws + 2097152);      // 1792x512 bf16 (1.75 MB)
  u16*   oT  = (u16*)(ws + 3932160);      // 512x512 bf16 (512 KB)
  float* Hke = (float*)(ws + 4456448);    // 2048x512 f32 (reused as h)
  float* Hqe = (float*)(ws + 8650752);    // 2048x512 f32 (reused as hln bf16)
  float* Hg  = (float*)(ws + 12845056);   // 2048x256 f32
  float* V   = (float*)(ws + 14942208);   // 2048x512 f32
  float* ubf = (float*)(ws + 19136512);   // 2048x64 f32
  float* abf = (float*)(ws + 19660800);   // 2048x64 f32
  float* P   = (float*)(ws + 20185088);   // 2*16*64*512 f32 = 4 MB (ends 24379392)
  float* h   = Hke;                       // overlay (Hke consumed by k_phase)
  u16*   hln = (u16*)Hqe;                 // overlay (Hqe consumed by k_phase)

  u16* keT = BTF;                // rows 0..511
  u16* qeT = BTF + 512*512;      // rows 512..1023
  u16* vT  = BTF + 1024*512;     // rows 1024..1535
  u16* gT  = BTF + 1536*512;     // rows 1536..1791

  k_prep<<<512 + 5*256, 256, 0, stream>>>(x, xb, ke_w1,qe_w1,v_w,gate_w1,out_w,
                                          keT,qeT,vT,gT,oT);
  k_gemm4<<<dim3(28,16),512,0,stream>>>(xb, BTF, ke_b1, qe_b1, v_b, gate_b1,
                                        Hke, Hqe, V, Hg);
  k_phase<<<512,256,0,stream>>>(Hke,Hqe,Hg, ke_w2,ke_b2, qe_w2,qe_b2,
                                gate_w2,gate_b2, setw,posw,freqs, ubf,abf);
  k_scanA<<<dim3(8,NCH,2),256,0,stream>>>(ubf, V, P);
  k_scanB<<<256,256,0,stream>>>(P);
  k_scanC<<<dim3(8,NCH,2),256,0,stream>>>(ubf, abf, V, P, h);
  k_ln<<<512,256,0,stream>>>(h, ln_g, ln_b, hln);
  k_gemm_out<<<dim3(8,32),256,0,stream>>>(hln, oT, out_b, x, out);
}